// Round 6
// baseline (142.107 us; speedup 1.0000x reference)
//
#include <hip/hip_runtime.h>

// LR_PINN_phase2_midout: fused 4-stage tiny MLP, N=262144, H=256, R=32.
// R24 = R23 + quad-shared rcp in all activation sites (single change).
//   R23 post-mortem: stagger NEUTRAL (67.6us = R19) -> the 17% issue-idle is
//   intra-wave dependency latency, not inter-wave LDS collision; with the
//   128-reg cap (R20 spill lesson) it is structural. So shrink the BUSY part:
//   VALUBusy ~111k cy/SIMD fits 2450 VALU@2cy + 2048 trans@~11cy per wave ->
//   the 1024 exp2 + 1024 rcp trans stream dominates the wall.
//   exp2 is irreducible (1/activation). rcp is shareable across a float4:
//     r = rcp(Ax*Ay*Az*Aw); 1/Ai reconstructed with 9 muls total.
//   Per quad: -3 rcp (33cy) + 9 mul (18cy) = -15cy; 256 quads/wave ->
//   ~-15k cy/SIMD ~= -6us predicted.
//   Accuracy: +~4ulp relative on inv (5e-7) << fp16 pack noise (5e-4).
//   Range note: product overflows only if sum of 4 y's > 128 (bench |y|<~20,
//   8+ sigma margin; the old per-element rcp(inf)=0 path was likewise
//   unreachable). absmax check guards this.
// Carried: K=32 MFMA chain (384 MFMA/wave-group) with pi/phi layout closure
// baked into staged weights; inv-feeding (-2/S folded); rowsum-init accs;
// 4 point-tile streams; one-time wave stagger (measured neutral, kept);
// hoisted first-group x/t load; NO setprio (R22: -7.5us, fences schedule).

typedef _Float16 half8_t __attribute__((ext_vector_type(8)));
typedef _Float16 half4_t __attribute__((ext_vector_type(4)));
typedef __fp16   fp16x2  __attribute__((ext_vector_type(2)));
typedef float    float4_t __attribute__((ext_vector_type(4)));

#define TANH_SCALE 2.885390081777927f  // 2*log2(e); exp2(S*x) == exp(2x)
#define MFMA32 __builtin_amdgcn_mfma_f32_16x16x32_f16

namespace {

struct alignas(16) Smem {
  // ctf entry e = ((k*8+T)*2+sel)*64+lane : half8 A-frag for GEMM1(k).
  //   A-row (P slot) r_phys = 8*(m>>2)+(m&3)+4*sel  (pi-permuted),
  //   cols H = 32T+8q+j, value = -2*alpha[r_phys]*Ct[r_phys][H].
  half8_t ctf[3 * 8 * 2 * 64];   // 48 KB
  // rwf entry e = (k*16+t')*64+lane : half8 A-frag for GEMM2(k).
  //   A-row H_phys = phi(t',m), cols r = 8q+j, value = S*R[H_phys][r].
  half8_t rwf[3 * 16 * 64];      // 48 KB
  float w0[256], w1[256], bb[256];  // physical-H order, pre-scaled by S
  float ew[256];                    // slot order: ew[16t'+i] = -2*end_w[phi(t',i)]
  float rsC[3 * 32];                // logical-slot rowsums
};

__device__ __forceinline__ half4_t pack4(float4_t v) {
  union { fp16x2 f2[2]; half4_t h4; } u;
  u.f2[0] = __builtin_amdgcn_cvt_pkrtz(v.x, v.y);
  u.f2[1] = __builtin_amdgcn_cvt_pkrtz(v.z, v.w);
  return u.h4;
}

__device__ __forceinline__ half8_t combine8(half4_t lo, half4_t hi) {
  union { half4_t h4[2]; half8_t h8; } u;
  u.h4[0] = lo; u.h4[1] = hi;
  return u.h8;
}

// Quad-shared reciprocal sigmoid core: inv_i = 1/(1+exp2(y_i)) for a float4,
// with ONE v_rcp_f32 (shared across the 4 denominators) instead of four.
// tanh(x) = 1 - 2*inv; the -2/+1 live in weights/sums (folded at staging).
__device__ __forceinline__ float4_t inv4q_f32(float4_t v) {
  float4_t A;
  A.x = __builtin_amdgcn_exp2f(v.x) + 1.0f;
  A.y = __builtin_amdgcn_exp2f(v.y) + 1.0f;
  A.z = __builtin_amdgcn_exp2f(v.z) + 1.0f;
  A.w = __builtin_amdgcn_exp2f(v.w) + 1.0f;
  const float pxy = A.x * A.y;
  const float pzw = A.z * A.w;
  const float r   = __builtin_amdgcn_rcpf(pxy * pzw);
  const float rxy = r * pzw;   // 1/(Ax*Ay)
  const float rzw = r * pxy;   // 1/(Az*Aw)
  float4_t o;
  o.x = rxy * A.y; o.y = rxy * A.x;
  o.z = rzw * A.w; o.w = rzw * A.z;
  return o;
}

__device__ __forceinline__ half4_t inv4(float4_t v) {
  return pack4(inv4q_f32(v));
}

__global__ __launch_bounds__(1024)
__attribute__((amdgpu_waves_per_eu(4, 4)))
void pinn_fused(
    const float* __restrict__ xg, const float* __restrict__ tg,
    const float* __restrict__ sw, const float* __restrict__ sb,
    const float* __restrict__ ewp, const float* __restrict__ ebp,
    const float* __restrict__ c0, const float* __restrict__ c1,
    const float* __restrict__ c2, const float* __restrict__ r0,
    const float* __restrict__ r1, const float* __restrict__ r2,
    const float* __restrict__ a0, const float* __restrict__ a1,
    const float* __restrict__ a2, float* __restrict__ out, int n)
{
  __shared__ Smem sm;
  const int tid = threadIdx.x;
  const int wave = tid >> 6;
  const int lane = tid & 63;
  const int m = lane & 15;   // point index (MFMA col / B-col)
  const int q = lane >> 4;   // quad
  const int wo = 4 * q;      // C/D row offset (slot i = 4q+reg)
  const int wo8 = 8 * q;     // frag k offset (k = 8q+j)
  const int tiles = n >> 4;

  // ---- first-group x/t loads issued BEFORE staging: HBM latency hides ----
  const int g0 = (blockIdx.x * 16 + wave) * 4;
  float xm[4], tm[4];
  if (g0 < tiles) {
#pragma unroll
    for (int s = 0; s < 4; ++s) {
      xm[s] = xg[(g0 + s) * 16 + m];
      tm[s] = tg[(g0 + s) * 16 + m];
    }
  }

  // ---- stage GEMM1 A-frags (ctf), pi-permuted rows, -2*alpha folded ----
  for (int e = tid; e < 3 * 8 * 2 * 64; e += 1024) {
    const int lane_ = e & 63;
    const int sel   = (e >> 6) & 1;
    const int T_    = (e >> 7) & 7;
    const int k_    = e >> 10;
    const int m_ = lane_ & 15, q_ = lane_ >> 4;
    const float* ck = (k_ == 0) ? c0 : (k_ == 1) ? c1 : c2;
    const float* ak = (k_ == 0) ? a0 : (k_ == 1) ? a1 : a2;
    const int rp_ = 8 * (m_ >> 2) + (m_ & 3) + 4 * sel;  // pi(sel*16+m)
    const float av = ak[rp_] * -2.0f;
    const int h0 = 32 * T_ + 8 * q_;
    half8_t v;
#pragma unroll
    for (int j = 0; j < 8; ++j)
      v[j] = (_Float16)(ck[(h0 + j) * 32 + rp_] * av);
    sm.ctf[e] = v;
  }
  // ---- stage GEMM2 A-frags (rwf), phi-permuted rows, S folded ----
  for (int e = tid; e < 3 * 16 * 64; e += 1024) {
    const int lane_ = e & 63;
    const int tp    = (e >> 6) & 15;
    const int k_    = e >> 10;
    const int m_ = lane_ & 15, q_ = lane_ >> 4;
    const float* rk = (k_ == 0) ? r0 : (k_ == 1) ? r1 : r2;
    const int hrow = 32 * (tp >> 1) + 8 * (m_ >> 2) + 4 * (tp & 1) + (m_ & 3);
    half8_t v;
#pragma unroll
    for (int j = 0; j < 8; ++j)
      v[j] = (_Float16)(rk[hrow * 32 + 8 * q_ + j] * TANH_SCALE);
    sm.rwf[e] = v;
  }
  if (tid < 256) {
    sm.w0[tid] = sw[2 * tid] * TANH_SCALE;
    sm.w1[tid] = sw[2 * tid + 1] * TANH_SCALE;
    sm.bb[tid] = sb[tid] * TANH_SCALE;
    const int tp = tid >> 4, ii = tid & 15;
    const int hph = 32 * (tp >> 1) + 8 * (ii >> 2) + 4 * (tp & 1) + (ii & 3);
    sm.ew[tid] = ewp[hph] * -2.0f;  // fold -2; slot-ordered via phi
  }
  __syncthreads();

  // ---- rowsums per logical slot: rsC[k][slot] = -0.5 * sum(ctf frags) ----
  if (tid < 96) {
    const int k_ = tid >> 5, r = tid & 31;
    const int sel = r >> 4, mm = r & 15;
    float s = 0.0f;
    for (int T = 0; T < 8; ++T)
      for (int qq = 0; qq < 4; ++qq) {
        const half8_t v = sm.ctf[((k_ * 8 + T) * 2 + sel) * 64 + 16 * qq + mm];
        float ps = 0.0f;
#pragma unroll
        for (int j = 0; j < 8; ++j) ps += (float)v[j];
        s += ps;
      }
    sm.rsC[k_ * 32 + r] = -0.5f * s;
  }
  __syncthreads();

  // ---- one-time wave de-phasing (measured neutral in R23; kept) ----
  {
    const int cohort = wave >> 2;  // 0..3
    if (cohort > 0) __builtin_amdgcn_s_sleep(7);
    if (cohort > 1) __builtin_amdgcn_s_sleep(7);
    if (cohort > 2) __builtin_amdgcn_s_sleep(7);
  }

  const float ebv = ebp[0];

  // per-lane ewsum: out = sum(ew)+sum((-2ew)*inv); sm.ew = -2*ew
  float ewsum = 0.0f;
  for (int t = 0; t < 16; ++t) {
    const float4_t e4 = *(const float4_t*)&sm.ew[t * 16 + wo];
    ewsum += e4.x + e4.y + e4.z + e4.w;
  }
  ewsum *= -0.5f;

  const float4_t z4 = {0.f, 0.f, 0.f, 0.f};

#pragma unroll 1
  for (int g = g0; g < tiles; g += 16384) {
    // ---- phase0 fused with GEMM1(0); 4 streams, accs init rowsums(0) ----
    const float4_t rs00 = *(const float4_t*)&sm.rsC[wo];
    const float4_t rs01 = *(const float4_t*)&sm.rsC[16 + wo];
    float4_t acc[4][2];
#pragma unroll
    for (int s = 0; s < 4; ++s) { acc[s][0] = rs00; acc[s][1] = rs01; }
    const half8_t* cp0 = &sm.ctf[lane];
#pragma unroll 1
    for (int T = 0; T < 8; ++T) {
      const int cb = 32 * T + wo8;
      const float4_t w0a = *(const float4_t*)&sm.w0[cb];
      const float4_t w0b = *(const float4_t*)&sm.w0[cb + 4];
      const float4_t w1a = *(const float4_t*)&sm.w1[cb];
      const float4_t w1b = *(const float4_t*)&sm.w1[cb + 4];
      const float4_t ba  = *(const float4_t*)&sm.bb[cb];
      const float4_t bb2 = *(const float4_t*)&sm.bb[cb + 4];
      half8_t h[4];
#pragma unroll
      for (int s = 0; s < 4; ++s) {
        float4_t za, zb;
        za.x = fmaf(xm[s], w0a.x, fmaf(tm[s], w1a.x, ba.x));
        za.y = fmaf(xm[s], w0a.y, fmaf(tm[s], w1a.y, ba.y));
        za.z = fmaf(xm[s], w0a.z, fmaf(tm[s], w1a.z, ba.z));
        za.w = fmaf(xm[s], w0a.w, fmaf(tm[s], w1a.w, ba.w));
        zb.x = fmaf(xm[s], w0b.x, fmaf(tm[s], w1b.x, bb2.x));
        zb.y = fmaf(xm[s], w0b.y, fmaf(tm[s], w1b.y, bb2.y));
        zb.z = fmaf(xm[s], w0b.z, fmaf(tm[s], w1b.z, bb2.z));
        zb.w = fmaf(xm[s], w0b.w, fmaf(tm[s], w1b.w, bb2.w));
        h[s] = combine8(inv4(za), inv4(zb));
      }
      const half8_t cA = cp0[0], cB = cp0[64];
#pragma unroll
      for (int s = 0; s < 4; ++s) acc[s][0] = MFMA32(cA, h[s], acc[s][0], 0, 0, 0);
#pragma unroll
      for (int s = 0; s < 4; ++s) acc[s][1] = MFMA32(cB, h[s], acc[s][1], 0, 0, 0);
      cp0 += 128;
    }

#pragma unroll 1
    for (int k = 0; k < 2; ++k) {
      // acc holds true P (rowsum init); pf = [pack4(acc0),pack4(acc1)] is
      // exactly the K=32 B-frag (k=8q+j = phys r) thanks to pi.
      half8_t pf[4];
#pragma unroll
      for (int s = 0; s < 4; ++s)
        pf[s] = combine8(pack4(acc[s][0]), pack4(acc[s][1]));
      const float4_t rsA = *(const float4_t*)&sm.rsC[(k + 1) * 32 + wo];
      const float4_t rsB = *(const float4_t*)&sm.rsC[(k + 1) * 32 + 16 + wo];
      float4_t nn[4][2];
#pragma unroll
      for (int s = 0; s < 4; ++s) { nn[s][0] = rsA; nn[s][1] = rsB; }
      const half8_t* rp = &sm.rwf[k * 1024 + lane];
      const half8_t* cp = &sm.ctf[(k + 1) * 1024 + lane];
#pragma unroll 1
      for (int t2 = 0; t2 < 8; ++t2) {
        const half8_t rA = rp[0], rB = rp[64];
        const half8_t cA = cp[0], cB = cp[64];
        float4_t u0[4];
#pragma unroll
        for (int s = 0; s < 4; ++s) u0[s] = MFMA32(rA, pf[s], z4, 0, 0, 0);
        half4_t hl[4];
#pragma unroll
        for (int s = 0; s < 4; ++s) hl[s] = inv4(u0[s]);
        float4_t u1[4];
#pragma unroll
        for (int s = 0; s < 4; ++s) u1[s] = MFMA32(rB, pf[s], z4, 0, 0, 0);
        half8_t h[4];
#pragma unroll
        for (int s = 0; s < 4; ++s) h[s] = combine8(hl[s], inv4(u1[s]));
#pragma unroll
        for (int s = 0; s < 4; ++s) nn[s][0] = MFMA32(cA, h[s], nn[s][0], 0, 0, 0);
#pragma unroll
        for (int s = 0; s < 4; ++s) nn[s][1] = MFMA32(cB, h[s], nn[s][1], 0, 0, 0);
        rp += 128; cp += 128;
      }
#pragma unroll
      for (int s = 0; s < 4; ++s) { acc[s][0] = nn[s][0]; acc[s][1] = nn[s][1]; }
    }

    // ---- k=2: GEMM2(2) (single K=32 MFMA per t') fused with end_w dot ----
    float ssum[4] = {ewsum, ewsum, ewsum, ewsum};
    {
      half8_t pf[4];
#pragma unroll
      for (int s = 0; s < 4; ++s)
        pf[s] = combine8(pack4(acc[s][0]), pack4(acc[s][1]));
      const half8_t* rp = &sm.rwf[2 * 1024 + lane];
#pragma unroll 1
      for (int tp = 0; tp < 16; ++tp) {
        const half8_t rA = rp[0];
        const float4_t ev = *(const float4_t*)&sm.ew[tp * 16 + wo];  // -2*ew
        float4_t u[4];
#pragma unroll
        for (int s = 0; s < 4; ++s) u[s] = MFMA32(rA, pf[s], z4, 0, 0, 0);
#pragma unroll
        for (int s = 0; s < 4; ++s) {
          const float4_t iv = inv4q_f32(u[s]);
          ssum[s] = fmaf(ev.x, iv.x, ssum[s]);
          ssum[s] = fmaf(ev.y, iv.y, ssum[s]);
          ssum[s] = fmaf(ev.z, iv.z, ssum[s]);
          ssum[s] = fmaf(ev.w, iv.w, ssum[s]);
        }
        rp += 64;
      }
    }

    // reduce each stream's partial dot over the 4 quads
#pragma unroll
    for (int s = 0; s < 4; ++s) {
      ssum[s] += __shfl_xor(ssum[s], 16);
      ssum[s] += __shfl_xor(ssum[s], 32);
    }
    if (lane < 16) {
#pragma unroll
      for (int s = 0; s < 4; ++s) out[(g + s) * 16 + m] = ssum[s] + ebv;
    }

    // refresh x/t for the next group (general-n correctness; dead at n=262144)
    const int gn = g + 16384;
    if (gn < tiles) {
#pragma unroll
      for (int s = 0; s < 4; ++s) {
        xm[s] = xg[(gn + s) * 16 + m];
        tm[s] = tg[(gn + s) * 16 + m];
      }
    }
  }
}

}  // namespace

extern "C" void kernel_launch(void* const* d_in, const int* in_sizes, int n_in,
                              void* d_out, int out_size, void* d_ws, size_t ws_size,
                              hipStream_t stream) {
  const float* xg  = (const float*)d_in[0];
  const float* tg  = (const float*)d_in[1];
  const float* sw  = (const float*)d_in[2];
  const float* sb  = (const float*)d_in[3];
  const float* ewp = (const float*)d_in[4];
  const float* ebp = (const float*)d_in[5];
  const float* c0  = (const float*)d_in[6];
  const float* c1  = (const float*)d_in[7];
  const float* c2  = (const float*)d_in[8];
  const float* r0  = (const float*)d_in[9];
  const float* r1  = (const float*)d_in[10];
  const float* r2  = (const float*)d_in[11];
  const float* a0  = (const float*)d_in[12];
  const float* a1  = (const float*)d_in[13];
  const float* a2  = (const float*)d_in[14];
  float* outp = (float*)d_out;

  const int n = in_sizes[0];  // 262144

  pinn_fused<<<256, 1024, 0, stream>>>(xg, tg, sw, sb, ewp, ebp,
                                       c0, c1, c2, r0, r1, r2, a0, a1, a2,
                                       outp, n);
}

// Round 7
// 137.561 us; speedup vs baseline: 1.0331x; 1.0331x over previous
//
#include <hip/hip_runtime.h>

// LR_PINN_phase2_midout: fused 4-stage tiny MLP, N=262144, H=256, R=32.
// R25 = exact revert to R23 (session best: 67.2-68.1us dispatch, absmax
// 7.3e-4). R24's quad-shared rcp regressed (+10.6us, VALU-busy +12k cy/SIMD):
// empirically rcp's issue cost <= ~3 muls and the shared-product serial chain
// (exp2->add->mul->mul->rcp->mul->mul) lengthened the MFMA->act->MFMA
// critical path. Reverted.
//
// Closed doors (counter-evidenced, this session):
//  - R20 reg-prefetch: spills (128-reg unified cap @4 waves/SIMD; accs=64).
//  - R22 setprio in hot loops: -7.5us (fences compiler MFMA/VALU interleave).
//  - R23 wave stagger: neutral (idle is intra-wave dep latency, not lockstep).
//  - R24 shared rcp: -10.6us (see above). 2:1 sharing also nets ~0.
//  - 32x32x16 port: analytically closed (per-SIMD MFMA occupancy scales with
//    flops: 19.4 vs 33.8 cy; instr-count halving buys nothing).
//  - Occupancy: locked at 4 waves/SIMD (100KB LDS -> 1 block/CU; 16-wave
//    block granularity; >4 waves needs <=102 regs, accs alone are 64).
// Pipe status: MFMA 24.4k cy/SIMD (at/under 29.8k ubench-derived flop floor);
// VALU 110k cy/SIMD (stream floor: 2048 trans + ~3000 VALU per wave); idle
// ~17% structural. This is the structure's measured floor.
//
// Design (carried): K=32 MFMA chain (384 MFMA/wave-group) with pi (r-dim) /
// phi (H-dim) layout closure baked into staged weights -> pf=pack(acc) IS the
// next B-frag; inv-feeding activation (exp2+add+rcp; -2/S folded into
// weights/sums); rowsum-init accs; 4 point-tile streams; fragment-ordered
// LDS (all hot reads base+lane*16, conflict-free; SQ_LDS_BANK_CONFLICT=0);
// hoisted first-group x/t load; one-time neutral stagger kept (harmless).

typedef _Float16 half8_t __attribute__((ext_vector_type(8)));
typedef _Float16 half4_t __attribute__((ext_vector_type(4)));
typedef __fp16   fp16x2  __attribute__((ext_vector_type(2)));
typedef float    float4_t __attribute__((ext_vector_type(4)));

#define TANH_SCALE 2.885390081777927f  // 2*log2(e); exp2(S*x) == exp(2x)
#define MFMA32 __builtin_amdgcn_mfma_f32_16x16x32_f16

namespace {

struct alignas(16) Smem {
  // ctf entry e = ((k*8+T)*2+sel)*64+lane : half8 A-frag for GEMM1(k).
  //   A-row (P slot) r_phys = 8*(m>>2)+(m&3)+4*sel  (pi-permuted),
  //   cols H = 32T+8q+j, value = -2*alpha[r_phys]*Ct[r_phys][H].
  half8_t ctf[3 * 8 * 2 * 64];   // 48 KB
  // rwf entry e = (k*16+t')*64+lane : half8 A-frag for GEMM2(k).
  //   A-row H_phys = phi(t',m), cols r = 8q+j, value = S*R[H_phys][r].
  half8_t rwf[3 * 16 * 64];      // 48 KB
  float w0[256], w1[256], bb[256];  // physical-H order, pre-scaled by S
  float ew[256];                    // slot order: ew[16t'+i] = -2*end_w[phi(t',i)]
  float rsC[3 * 32];                // logical-slot rowsums
};

__device__ __forceinline__ half4_t pack4(float4_t v) {
  union { fp16x2 f2[2]; half4_t h4; } u;
  u.f2[0] = __builtin_amdgcn_cvt_pkrtz(v.x, v.y);
  u.f2[1] = __builtin_amdgcn_cvt_pkrtz(v.z, v.w);
  return u.h4;
}

__device__ __forceinline__ half8_t combine8(half4_t lo, half4_t hi) {
  union { half4_t h4[2]; half8_t h8; } u;
  u.h4[0] = lo; u.h4[1] = hi;
  return u.h8;
}

// inv = 1/(1+exp2(y)); tanh(x) = 1 - 2*inv (the -2/+1 live in weights/sums).
// No clamp: e=inf -> rcp(inf)=0 exact; e->0 -> inv->1 exact.
__device__ __forceinline__ float inv_pre(float y) {
  return __builtin_amdgcn_rcpf(__builtin_amdgcn_exp2f(y) + 1.0f);
}

__device__ __forceinline__ half4_t inv4(float4_t v) {
  float4_t r;
  r.x = inv_pre(v.x); r.y = inv_pre(v.y);
  r.z = inv_pre(v.z); r.w = inv_pre(v.w);
  return pack4(r);
}

__global__ __launch_bounds__(1024)
__attribute__((amdgpu_waves_per_eu(4, 4)))
void pinn_fused(
    const float* __restrict__ xg, const float* __restrict__ tg,
    const float* __restrict__ sw, const float* __restrict__ sb,
    const float* __restrict__ ewp, const float* __restrict__ ebp,
    const float* __restrict__ c0, const float* __restrict__ c1,
    const float* __restrict__ c2, const float* __restrict__ r0,
    const float* __restrict__ r1, const float* __restrict__ r2,
    const float* __restrict__ a0, const float* __restrict__ a1,
    const float* __restrict__ a2, float* __restrict__ out, int n)
{
  __shared__ Smem sm;
  const int tid = threadIdx.x;
  const int wave = tid >> 6;
  const int lane = tid & 63;
  const int m = lane & 15;   // point index (MFMA col / B-col)
  const int q = lane >> 4;   // quad
  const int wo = 4 * q;      // C/D row offset (slot i = 4q+reg)
  const int wo8 = 8 * q;     // frag k offset (k = 8q+j)
  const int tiles = n >> 4;

  // ---- first-group x/t loads issued BEFORE staging: HBM latency hides ----
  const int g0 = (blockIdx.x * 16 + wave) * 4;
  float xm[4], tm[4];
  if (g0 < tiles) {
#pragma unroll
    for (int s = 0; s < 4; ++s) {
      xm[s] = xg[(g0 + s) * 16 + m];
      tm[s] = tg[(g0 + s) * 16 + m];
    }
  }

  // ---- stage GEMM1 A-frags (ctf), pi-permuted rows, -2*alpha folded ----
  for (int e = tid; e < 3 * 8 * 2 * 64; e += 1024) {
    const int lane_ = e & 63;
    const int sel   = (e >> 6) & 1;
    const int T_    = (e >> 7) & 7;
    const int k_    = e >> 10;
    const int m_ = lane_ & 15, q_ = lane_ >> 4;
    const float* ck = (k_ == 0) ? c0 : (k_ == 1) ? c1 : c2;
    const float* ak = (k_ == 0) ? a0 : (k_ == 1) ? a1 : a2;
    const int rp_ = 8 * (m_ >> 2) + (m_ & 3) + 4 * sel;  // pi(sel*16+m)
    const float av = ak[rp_] * -2.0f;
    const int h0 = 32 * T_ + 8 * q_;
    half8_t v;
#pragma unroll
    for (int j = 0; j < 8; ++j)
      v[j] = (_Float16)(ck[(h0 + j) * 32 + rp_] * av);
    sm.ctf[e] = v;
  }
  // ---- stage GEMM2 A-frags (rwf), phi-permuted rows, S folded ----
  for (int e = tid; e < 3 * 16 * 64; e += 1024) {
    const int lane_ = e & 63;
    const int tp    = (e >> 6) & 15;
    const int k_    = e >> 10;
    const int m_ = lane_ & 15, q_ = lane_ >> 4;
    const float* rk = (k_ == 0) ? r0 : (k_ == 1) ? r1 : r2;
    const int hrow = 32 * (tp >> 1) + 8 * (m_ >> 2) + 4 * (tp & 1) + (m_ & 3);
    half8_t v;
#pragma unroll
    for (int j = 0; j < 8; ++j)
      v[j] = (_Float16)(rk[hrow * 32 + 8 * q_ + j] * TANH_SCALE);
    sm.rwf[e] = v;
  }
  if (tid < 256) {
    sm.w0[tid] = sw[2 * tid] * TANH_SCALE;
    sm.w1[tid] = sw[2 * tid + 1] * TANH_SCALE;
    sm.bb[tid] = sb[tid] * TANH_SCALE;
    const int tp = tid >> 4, ii = tid & 15;
    const int hph = 32 * (tp >> 1) + 8 * (ii >> 2) + 4 * (tp & 1) + (ii & 3);
    sm.ew[tid] = ewp[hph] * -2.0f;  // fold -2; slot-ordered via phi
  }
  __syncthreads();

  // ---- rowsums per logical slot: rsC[k][slot] = -0.5 * sum(ctf frags) ----
  if (tid < 96) {
    const int k_ = tid >> 5, r = tid & 31;
    const int sel = r >> 4, mm = r & 15;
    float s = 0.0f;
    for (int T = 0; T < 8; ++T)
      for (int qq = 0; qq < 4; ++qq) {
        const half8_t v = sm.ctf[((k_ * 8 + T) * 2 + sel) * 64 + 16 * qq + mm];
        float ps = 0.0f;
#pragma unroll
        for (int j = 0; j < 8; ++j) ps += (float)v[j];
        s += ps;
      }
    sm.rsC[k_ * 32 + r] = -0.5f * s;
  }
  __syncthreads();

  // ---- one-time wave de-phasing (measured neutral; kept, harmless) ----
  {
    const int cohort = wave >> 2;  // 0..3
    if (cohort > 0) __builtin_amdgcn_s_sleep(7);
    if (cohort > 1) __builtin_amdgcn_s_sleep(7);
    if (cohort > 2) __builtin_amdgcn_s_sleep(7);
  }

  const float ebv = ebp[0];

  // per-lane ewsum: out = sum(ew)+sum((-2ew)*inv); sm.ew = -2*ew
  float ewsum = 0.0f;
  for (int t = 0; t < 16; ++t) {
    const float4_t e4 = *(const float4_t*)&sm.ew[t * 16 + wo];
    ewsum += e4.x + e4.y + e4.z + e4.w;
  }
  ewsum *= -0.5f;

  const float4_t z4 = {0.f, 0.f, 0.f, 0.f};

#pragma unroll 1
  for (int g = g0; g < tiles; g += 16384) {
    // ---- phase0 fused with GEMM1(0); 4 streams, accs init rowsums(0) ----
    const float4_t rs00 = *(const float4_t*)&sm.rsC[wo];
    const float4_t rs01 = *(const float4_t*)&sm.rsC[16 + wo];
    float4_t acc[4][2];
#pragma unroll
    for (int s = 0; s < 4; ++s) { acc[s][0] = rs00; acc[s][1] = rs01; }
    const half8_t* cp0 = &sm.ctf[lane];
#pragma unroll 1
    for (int T = 0; T < 8; ++T) {
      const int cb = 32 * T + wo8;
      const float4_t w0a = *(const float4_t*)&sm.w0[cb];
      const float4_t w0b = *(const float4_t*)&sm.w0[cb + 4];
      const float4_t w1a = *(const float4_t*)&sm.w1[cb];
      const float4_t w1b = *(const float4_t*)&sm.w1[cb + 4];
      const float4_t ba  = *(const float4_t*)&sm.bb[cb];
      const float4_t bb2 = *(const float4_t*)&sm.bb[cb + 4];
      half8_t h[4];
#pragma unroll
      for (int s = 0; s < 4; ++s) {
        float4_t za, zb;
        za.x = fmaf(xm[s], w0a.x, fmaf(tm[s], w1a.x, ba.x));
        za.y = fmaf(xm[s], w0a.y, fmaf(tm[s], w1a.y, ba.y));
        za.z = fmaf(xm[s], w0a.z, fmaf(tm[s], w1a.z, ba.z));
        za.w = fmaf(xm[s], w0a.w, fmaf(tm[s], w1a.w, ba.w));
        zb.x = fmaf(xm[s], w0b.x, fmaf(tm[s], w1b.x, bb2.x));
        zb.y = fmaf(xm[s], w0b.y, fmaf(tm[s], w1b.y, bb2.y));
        zb.z = fmaf(xm[s], w0b.z, fmaf(tm[s], w1b.z, bb2.z));
        zb.w = fmaf(xm[s], w0b.w, fmaf(tm[s], w1b.w, bb2.w));
        h[s] = combine8(inv4(za), inv4(zb));
      }
      const half8_t cA = cp0[0], cB = cp0[64];
#pragma unroll
      for (int s = 0; s < 4; ++s) acc[s][0] = MFMA32(cA, h[s], acc[s][0], 0, 0, 0);
#pragma unroll
      for (int s = 0; s < 4; ++s) acc[s][1] = MFMA32(cB, h[s], acc[s][1], 0, 0, 0);
      cp0 += 128;
    }

#pragma unroll 1
    for (int k = 0; k < 2; ++k) {
      // acc holds true P (rowsum init); pf = [pack4(acc0),pack4(acc1)] is
      // exactly the K=32 B-frag (k=8q+j = phys r) thanks to pi.
      half8_t pf[4];
#pragma unroll
      for (int s = 0; s < 4; ++s)
        pf[s] = combine8(pack4(acc[s][0]), pack4(acc[s][1]));
      const float4_t rsA = *(const float4_t*)&sm.rsC[(k + 1) * 32 + wo];
      const float4_t rsB = *(const float4_t*)&sm.rsC[(k + 1) * 32 + 16 + wo];
      float4_t nn[4][2];
#pragma unroll
      for (int s = 0; s < 4; ++s) { nn[s][0] = rsA; nn[s][1] = rsB; }
      const half8_t* rp = &sm.rwf[k * 1024 + lane];
      const half8_t* cp = &sm.ctf[(k + 1) * 1024 + lane];
#pragma unroll 1
      for (int t2 = 0; t2 < 8; ++t2) {
        const half8_t rA = rp[0], rB = rp[64];
        const half8_t cA = cp[0], cB = cp[64];
        float4_t u0[4];
#pragma unroll
        for (int s = 0; s < 4; ++s) u0[s] = MFMA32(rA, pf[s], z4, 0, 0, 0);
        half4_t hl[4];
#pragma unroll
        for (int s = 0; s < 4; ++s) hl[s] = inv4(u0[s]);
        float4_t u1[4];
#pragma unroll
        for (int s = 0; s < 4; ++s) u1[s] = MFMA32(rB, pf[s], z4, 0, 0, 0);
        half8_t h[4];
#pragma unroll
        for (int s = 0; s < 4; ++s) h[s] = combine8(hl[s], inv4(u1[s]));
#pragma unroll
        for (int s = 0; s < 4; ++s) nn[s][0] = MFMA32(cA, h[s], nn[s][0], 0, 0, 0);
#pragma unroll
        for (int s = 0; s < 4; ++s) nn[s][1] = MFMA32(cB, h[s], nn[s][1], 0, 0, 0);
        rp += 128; cp += 128;
      }
#pragma unroll
      for (int s = 0; s < 4; ++s) { acc[s][0] = nn[s][0]; acc[s][1] = nn[s][1]; }
    }

    // ---- k=2: GEMM2(2) (single K=32 MFMA per t') fused with end_w dot ----
    float ssum[4] = {ewsum, ewsum, ewsum, ewsum};
    {
      half8_t pf[4];
#pragma unroll
      for (int s = 0; s < 4; ++s)
        pf[s] = combine8(pack4(acc[s][0]), pack4(acc[s][1]));
      const half8_t* rp = &sm.rwf[2 * 1024 + lane];
#pragma unroll 1
      for (int tp = 0; tp < 16; ++tp) {
        const half8_t rA = rp[0];
        const float4_t ev = *(const float4_t*)&sm.ew[tp * 16 + wo];  // -2*ew
        float4_t u[4];
#pragma unroll
        for (int s = 0; s < 4; ++s) u[s] = MFMA32(rA, pf[s], z4, 0, 0, 0);
#pragma unroll
        for (int s = 0; s < 4; ++s) {
          ssum[s] = fmaf(ev.x, inv_pre(u[s].x), ssum[s]);
          ssum[s] = fmaf(ev.y, inv_pre(u[s].y), ssum[s]);
          ssum[s] = fmaf(ev.z, inv_pre(u[s].z), ssum[s]);
          ssum[s] = fmaf(ev.w, inv_pre(u[s].w), ssum[s]);
        }
        rp += 64;
      }
    }

    // reduce each stream's partial dot over the 4 quads
#pragma unroll
    for (int s = 0; s < 4; ++s) {
      ssum[s] += __shfl_xor(ssum[s], 16);
      ssum[s] += __shfl_xor(ssum[s], 32);
    }
    if (lane < 16) {
#pragma unroll
      for (int s = 0; s < 4; ++s) out[(g + s) * 16 + m] = ssum[s] + ebv;
    }

    // refresh x/t for the next group (general-n correctness; dead at n=262144)
    const int gn = g + 16384;
    if (gn < tiles) {
#pragma unroll
      for (int s = 0; s < 4; ++s) {
        xm[s] = xg[(gn + s) * 16 + m];
        tm[s] = tg[(gn + s) * 16 + m];
      }
    }
  }
}

}  // namespace

extern "C" void kernel_launch(void* const* d_in, const int* in_sizes, int n_in,
                              void* d_out, int out_size, void* d_ws, size_t ws_size,
                              hipStream_t stream) {
  const float* xg  = (const float*)d_in[0];
  const float* tg  = (const float*)d_in[1];
  const float* sw  = (const float*)d_in[2];
  const float* sb  = (const float*)d_in[3];
  const float* ewp = (const float*)d_in[4];
  const float* ebp = (const float*)d_in[5];
  const float* c0  = (const float*)d_in[6];
  const float* c1  = (const float*)d_in[7];
  const float* c2  = (const float*)d_in[8];
  const float* r0  = (const float*)d_in[9];
  const float* r1  = (const float*)d_in[10];
  const float* r2  = (const float*)d_in[11];
  const float* a0  = (const float*)d_in[12];
  const float* a1  = (const float*)d_in[13];
  const float* a2  = (const float*)d_in[14];
  float* outp = (float*)d_out;

  const int n = in_sizes[0];  // 262144

  pinn_fused<<<256, 1024, 0, stream>>>(xg, tg, sw, sb, ewp, ebp,
                                       c0, c1, c2, r0, r1, r2, a0, a1, a2,
                                       outp, n);
}